// Round 4
// baseline (1289.829 us; speedup 1.0000x reference)
//
#include <hip/hip_runtime.h>
#include <math.h>

#define N_NODES 100000
#define F 32
#define BUCKET 64                    // nodes per bucket
#define NB ((N_NODES + BUCKET - 1) / BUCKET)   // 1563
#define CAP 1280                     // mean 1024 + 8 sigma

// ---------------- bin edges by target bucket ----------------
// packed entry: (col_local << 17) | row   (row < 2^17, col_local < 64)
__global__ void bin_kernel(const int* __restrict__ row, const int* __restrict__ col,
                           int* __restrict__ bcount, unsigned* __restrict__ storage, int E) {
    int e = blockIdx.x * blockDim.x + threadIdx.x;
    if (e >= E) return;
    int c = col[e];
    int r = row[e];
    int b = c >> 6;
    int pos = atomicAdd(&bcount[b], 1);
    if (pos < CAP)
        storage[(size_t)b * CAP + pos] = ((unsigned)(c & 63) << 17) | (unsigned)r;
}

// ---------------- per-bucket degree histogram -> dis ----------------
__global__ void bucket_dis_kernel(const unsigned* __restrict__ storage, const int* __restrict__ bcount,
                                  float* __restrict__ dis, int n) {
    __shared__ int hist[BUCKET];
    int tid = threadIdx.x;
    int b = blockIdx.x;
    if (tid < BUCKET) hist[tid] = 0;
    __syncthreads();
    int cnt = bcount[b];
    if (cnt > CAP) cnt = CAP;
    const unsigned* st = storage + (size_t)b * CAP;
    for (int i = tid; i < cnt; i += 256) atomicAdd(&hist[st[i] >> 17], 1);
    __syncthreads();
    if (tid < BUCKET) {
        int node = b * BUCKET + tid;
        if (node < n) {
            int d = hist[tid];
            dis[node] = (d > 0) ? rsqrtf((float)d) : 0.0f;
        }
    }
}

// ---------------- layer 1 transform: t = x @ W1 (x is N x 5) ----------------
__global__ void transform1_kernel(const float* __restrict__ x, const float* __restrict__ W,
                                  float* __restrict__ t, int n) {
    __shared__ float Ws[5 * F];
    int tid = threadIdx.x;
    if (tid < 5 * F) Ws[tid] = W[tid];
    __syncthreads();
    int gid = blockIdx.x * blockDim.x + tid;
    int node = gid >> 5;
    int f = gid & 31;
    if (node >= n) return;
    float acc = 0.0f;
#pragma unroll
    for (int k = 0; k < 5; k++) acc += x[node * 5 + k] * Ws[k * F + f];
    t[(size_t)node * F + f] = acc;
}

// ---------------- fused relu(h + b) @ W  (h is N x 32) ----------------
__global__ void transform_relu_kernel(const float* __restrict__ h, const float* __restrict__ b,
                                      const float* __restrict__ W, float* __restrict__ t, int n) {
    __shared__ float Ws[F * F];
    __shared__ float hs[256];
    int tid = threadIdx.x;
    for (int i = tid; i < F * F; i += 256) Ws[i] = W[i];
    int node = blockIdx.x * 8 + (tid >> 5);
    int f = tid & 31;
    float hv = 0.0f;
    if (node < n) hv = h[(size_t)node * F + f] + b[f];
    hs[tid] = hv > 0.0f ? hv : 0.0f;
    __syncthreads();
    if (node >= n) return;
    const float* hrow = &hs[(tid >> 5) << 5];
    float acc = 0.0f;
#pragma unroll
    for (int k = 0; k < F; k++) acc += hrow[k] * Ws[k * F + f];
    t[(size_t)node * F + f] = acc;
}

// ---------------- bucket gather with LDS accumulation ----------------
// Block = one bucket. acc[64][32] in LDS; 8 groups of 32 lanes stream edges.
__global__ void gather_bucket_kernel(const float* __restrict__ t, const unsigned* __restrict__ storage,
                                     const int* __restrict__ bcount, const float* __restrict__ dis,
                                     float* __restrict__ h, int n) {
    __shared__ float acc[BUCKET * F];   // 8 KB
    int tid = threadIdx.x;
    int b = blockIdx.x;
    for (int i = tid; i < BUCKET * F; i += 256) acc[i] = 0.0f;
    __syncthreads();
    int cnt = bcount[b];
    if (cnt > CAP) cnt = CAP;
    int g = tid >> 5;       // group 0..7
    int f = tid & 31;       // feature lane
    const unsigned* st = storage + (size_t)b * CAP;
    int i = g;
    for (; i + 8 < cnt; i += 16) {
        unsigned p0 = st[i];
        unsigned p1 = st[i + 8];
        int r0 = p0 & 0x1FFFF, l0 = p0 >> 17;
        int r1 = p1 & 0x1FFFF, l1 = p1 >> 17;
        float v0 = dis[r0] * t[(size_t)r0 * F + f];
        float v1 = dis[r1] * t[(size_t)r1 * F + f];
        atomicAdd(&acc[l0 * F + f], v0);
        atomicAdd(&acc[l1 * F + f], v1);
    }
    for (; i < cnt; i += 8) {
        unsigned p0 = st[i];
        int r0 = p0 & 0x1FFFF, l0 = p0 >> 17;
        atomicAdd(&acc[l0 * F + f], dis[r0] * t[(size_t)r0 * F + f]);
    }
    __syncthreads();
    int base = b * BUCKET;
    for (int nl = g; nl < BUCKET; nl += 8) {
        int node = base + nl;
        if (node < n) h[(size_t)node * F + f] = acc[nl * F + f] * dis[node];
    }
}

// ---------------- heads: distance/attention per node + block argmax partials ----------------
__global__ void heads_kernel(const float* __restrict__ h, const float* __restrict__ b3,
                             const float* __restrict__ Wd, const float* __restrict__ bd,
                             const float* __restrict__ Wa, const float* __restrict__ ba,
                             float* __restrict__ out, float* __restrict__ pmax,
                             int* __restrict__ pidx, int n) {
    int tid = threadIdx.x;
    int node = blockIdx.x * blockDim.x + tid;
    float att = -INFINITY;
    int myidx = 0x7fffffff;
    if (node < n) {
        float dacc = 0.0f, aacc = 0.0f;
#pragma unroll
        for (int k = 0; k < F; k++) {
            float hv = h[(size_t)node * F + k] + b3[k];
            hv = hv > 0.0f ? hv : 0.0f;
            dacc += hv * Wd[k];
            aacc += hv * Wa[k];
        }
        dacc += bd[0];
        aacc += ba[0];
        out[node] = dacc;
        out[N_NODES + node] = aacc;
        att = aacc;
        myidx = node;
    }
    __shared__ float smax[256];
    __shared__ int sidx[256];
    smax[tid] = att;
    sidx[tid] = myidx;
    __syncthreads();
    for (int s = 128; s > 0; s >>= 1) {
        if (tid < s) {
            float v2 = smax[tid + s];
            int i2 = sidx[tid + s];
            if (v2 > smax[tid] || (v2 == smax[tid] && i2 < sidx[tid])) {
                smax[tid] = v2;
                sidx[tid] = i2;
            }
        }
        __syncthreads();
    }
    if (tid == 0) {
        pmax[blockIdx.x] = smax[0];
        pidx[blockIdx.x] = sidx[0];
    }
}

// ---------------- final: reduce partials, compute target head outputs ----------------
__global__ void final_kernel(const float* __restrict__ pmax, const int* __restrict__ pidx,
                             int nblocks, const float* __restrict__ h, const float* __restrict__ b3,
                             const float* __restrict__ Wt, const float* __restrict__ bt,
                             const float* __restrict__ Wact, const float* __restrict__ bact,
                             float* __restrict__ out) {
    __shared__ float smax[256];
    __shared__ int sidx[256];
    int tid = threadIdx.x;
    float best = -INFINITY;
    int bidx = 0x7fffffff;
    for (int i = tid; i < nblocks; i += 256) {
        float v = pmax[i];
        int ix = pidx[i];
        if (v > best || (v == best && ix < bidx)) { best = v; bidx = ix; }
    }
    smax[tid] = best;
    sidx[tid] = bidx;
    __syncthreads();
    for (int s = 128; s > 0; s >>= 1) {
        if (tid < s) {
            float v2 = smax[tid + s];
            int i2 = sidx[tid + s];
            if (v2 > smax[tid] || (v2 == smax[tid] && i2 < sidx[tid])) {
                smax[tid] = v2;
                sidx[tid] = i2;
            }
        }
        __syncthreads();
    }
    __shared__ float ht[F];
    if (tid < F) {
        float hv = h[(size_t)sidx[0] * F + tid] + b3[tid];
        ht[tid] = hv > 0.0f ? hv : 0.0f;
    }
    __syncthreads();
    if (tid < 2) {
        float acc = bt[tid];
#pragma unroll
        for (int k = 0; k < F; k++) acc += ht[k] * Wt[k * 2 + tid];
        out[2 * N_NODES + tid] = acc;
    } else if (tid < 11) {
        int j = tid - 2;
        float acc = bact[j];
#pragma unroll
        for (int k = 0; k < F; k++) acc += ht[k] * Wact[k * 9 + j];
        out[2 * N_NODES + 2 + j] = acc;
    }
}

extern "C" void kernel_launch(void* const* d_in, const int* in_sizes, int n_in,
                              void* d_out, int out_size, void* d_ws, size_t ws_size,
                              hipStream_t stream) {
    const float* x  = (const float*)d_in[0];
    const int*   ei = (const int*)d_in[1];
    const int E = in_sizes[1] / 2;
    const int* row = ei;
    const int* col = ei + E;
    const float* W1 = (const float*)d_in[2];
    const float* b1 = (const float*)d_in[3];
    const float* W2 = (const float*)d_in[4];
    const float* b2 = (const float*)d_in[5];
    const float* W3 = (const float*)d_in[6];
    const float* b3 = (const float*)d_in[7];
    const float* Wd = (const float*)d_in[8];
    const float* bd = (const float*)d_in[9];
    const float* Wa = (const float*)d_in[10];
    const float* ba = (const float*)d_in[11];
    const float* Wt = (const float*)d_in[12];
    const float* bt = (const float*)d_in[13];
    const float* Wact = (const float*)d_in[14];
    const float* bact = (const float*)d_in[15];

    float* out = (float*)d_out;
    float* ws  = (float*)d_ws;

    // workspace layout
    float*    dis     = ws;                                   // N
    float*    t       = ws + N_NODES;                         // N*F
    float*    h       = t + (size_t)N_NODES * F;              // N*F
    int*      bcount  = (int*)(h + (size_t)N_NODES * F);      // NB
    unsigned* storage = (unsigned*)(bcount + ((NB + 63) & ~63)); // NB*CAP
    float*    pmax    = (float*)(storage + (size_t)NB * CAP); // <=512
    int*      pidx    = (int*)(pmax + 512);                   // <=512

    const int B = 256;
    const int nblocks_heads = (N_NODES + B - 1) / B;
    const int nblocks_nodes = (N_NODES + 7) / 8;

    // ---- bin edges (once per call, used 3x) ----
    hipMemsetAsync(bcount, 0, (size_t)NB * sizeof(int), stream);
    bin_kernel<<<(E + B - 1) / B, B, 0, stream>>>(row, col, bcount, storage, E);
    bucket_dis_kernel<<<NB, B, 0, stream>>>(storage, bcount, dis, N_NODES);

    // ---- layer 1 ----
    transform1_kernel<<<((size_t)N_NODES * F + B - 1) / B, B, 0, stream>>>(x, W1, t, N_NODES);
    gather_bucket_kernel<<<NB, B, 0, stream>>>(t, storage, bcount, dis, h, N_NODES);

    // ---- layer 2 ----
    transform_relu_kernel<<<nblocks_nodes, B, 0, stream>>>(h, b1, W2, t, N_NODES);
    gather_bucket_kernel<<<NB, B, 0, stream>>>(t, storage, bcount, dis, h, N_NODES);

    // ---- layer 3 ----
    transform_relu_kernel<<<nblocks_nodes, B, 0, stream>>>(h, b2, W3, t, N_NODES);
    gather_bucket_kernel<<<NB, B, 0, stream>>>(t, storage, bcount, dis, h, N_NODES);

    // ---- heads + argmax ----
    heads_kernel<<<nblocks_heads, B, 0, stream>>>(h, b3, Wd, bd, Wa, ba, out, pmax, pidx, N_NODES);
    final_kernel<<<1, B, 0, stream>>>(pmax, pidx, nblocks_heads, h, b3, Wt, bt, Wact, bact, out);
}

// Round 5
// 353.113 us; speedup vs baseline: 3.6527x; 3.6527x over previous
//
#include <hip/hip_runtime.h>
#include <math.h>

#define N_NODES 100000
#define F 32
#define BUCKET 64
#define NB ((N_NODES + BUCKET - 1) / BUCKET)   // 1563
#define NREP 8
#define RCAP 192        // per-replica cap: mean 128 + ~5.7 sigma

// ---------------- bin edges by (target bucket, replica) ----------------
// packed entry: (col_local << 17) | row
__global__ void bin_kernel(const int* __restrict__ row, const int* __restrict__ col,
                           int* __restrict__ bcount, unsigned* __restrict__ storage, int E) {
    int e = blockIdx.x * 256 + threadIdx.x;
    if (e >= E) return;
    int c = col[e], r = row[e];
    int slot = (c >> 6) * NREP + (e & (NREP - 1));
    int pos = atomicAdd(&bcount[slot], 1);
    if (pos < RCAP)
        storage[(size_t)slot * RCAP + pos] = ((unsigned)(c & 63) << 17) | (unsigned)r;
}

// ---------------- exclusive scan of per-bucket totals (1 block) ----------------
__global__ void bscan_kernel(const int* __restrict__ bcount, int* __restrict__ bbase,
                             int* __restrict__ rowstart) {
    __shared__ int sh[1024];
    int tid = threadIdx.x;
    int b0 = 2 * tid, b1 = 2 * tid + 1;
    int t0 = 0, t1 = 0;
    if (b0 < NB) for (int r = 0; r < NREP; r++) { int c = bcount[b0 * NREP + r]; t0 += (c > RCAP ? RCAP : c); }
    if (b1 < NB) for (int r = 0; r < NREP; r++) { int c = bcount[b1 * NREP + r]; t1 += (c > RCAP ? RCAP : c); }
    int s = t0 + t1;
    sh[tid] = s;
    __syncthreads();
    for (int off = 1; off < 1024; off <<= 1) {
        int v = (tid >= off) ? sh[tid - off] : 0;
        __syncthreads();
        sh[tid] += v;
        __syncthreads();
    }
    int excl = sh[tid] - s;
    if (b0 < NB) bbase[b0] = excl;
    if (b1 < NB) bbase[b1] = excl + t0;
    if (tid == 1023) rowstart[N_NODES] = sh[1023];
}

// ---------------- per-bucket LDS counting sort -> CSR + dis ----------------
__global__ void csr_build_kernel(const unsigned* __restrict__ storage, const int* __restrict__ bcount,
                                 const int* __restrict__ bbase, int* __restrict__ rowstart,
                                 int* __restrict__ csr_src, float* __restrict__ dis, int n) {
    __shared__ unsigned sh[NREP * RCAP];
    __shared__ int outloc[NREP * RCAP];
    __shared__ int repbase[NREP + 1];
    __shared__ int hist[BUCKET];
    __shared__ int pre[BUCKET];
    __shared__ int cur[BUCKET];
    int b = blockIdx.x, tid = threadIdx.x;
    if (tid < BUCKET) hist[tid] = 0;
    if (tid == 0) {
        int s = 0;
        for (int r = 0; r < NREP; r++) {
            repbase[r] = s;
            int c = bcount[b * NREP + r];
            s += (c > RCAP ? RCAP : c);
        }
        repbase[NREP] = s;
    }
    __syncthreads();
    int g = tid >> 5, lane = tid & 31;
    {
        int cbeg = repbase[g];
        int clen = repbase[g + 1] - cbeg;
        const unsigned* st = storage + (size_t)(b * NREP + g) * RCAP;
        for (int i = lane; i < clen; i += 32) sh[cbeg + i] = st[i];
    }
    __syncthreads();
    int tot = repbase[NREP];
    for (int i = tid; i < tot; i += 256) atomicAdd(&hist[sh[i] >> 17], 1);
    __syncthreads();
    if (tid < BUCKET) pre[tid] = hist[tid];
    __syncthreads();
    for (int off = 1; off < BUCKET; off <<= 1) {
        int v = 0;
        if (tid < BUCKET && tid >= off) v = pre[tid - off];
        __syncthreads();
        if (tid < BUCKET && tid >= off) pre[tid] += v;
        __syncthreads();
    }
    int base = bbase[b];
    if (tid < BUCKET) {
        int excl = pre[tid] - hist[tid];
        cur[tid] = excl;
        int node = b * BUCKET + tid;
        if (node < n) {
            rowstart[node] = base + excl;
            int d = hist[tid];
            dis[node] = (d > 0) ? rsqrtf((float)d) : 0.0f;
        }
    }
    __syncthreads();
    for (int i = tid; i < tot; i += 256) {
        unsigned p = sh[i];
        int pos = atomicAdd(&cur[p >> 17], 1);
        outloc[pos] = (int)(p & 0x1FFFF);
    }
    __syncthreads();
    for (int i = tid; i < tot; i += 256) csr_src[base + i] = outloc[i];
}

// ---------------- xd = dis[node] * x row, padded to 8 floats ----------------
__global__ void xd_kernel(const float* __restrict__ x, const float* __restrict__ dis,
                          float* __restrict__ xd, int n) {
    int gid = blockIdx.x * 256 + threadIdx.x;
    if (gid >= n * 8) return;
    int node = gid >> 3, f = gid & 7;
    xd[gid] = (f < 5) ? dis[node] * x[node * 5 + f] : 0.0f;
}

// ---------------- layer-1 gather: s1[v] = sum xd[r]  (8-wide rows) ----------------
__global__ void gather8_kernel(const float* __restrict__ xd, const int* __restrict__ rowstart,
                               const int* __restrict__ csr_src, float* __restrict__ s1, int n) {
    int tid = threadIdx.x;
    int node = blockIdx.x * 32 + (tid >> 3);
    if (node >= n) return;
    int f = tid & 7;
    int start = rowstart[node], end = rowstart[node + 1];
    float a0 = 0, a1 = 0, a2 = 0, a3 = 0, a4 = 0, a5 = 0, a6 = 0, a7 = 0;
    int i = start;
    for (; i + 7 < end; i += 8) {
        int r0 = csr_src[i], r1 = csr_src[i+1], r2 = csr_src[i+2], r3 = csr_src[i+3];
        int r4 = csr_src[i+4], r5 = csr_src[i+5], r6 = csr_src[i+6], r7 = csr_src[i+7];
        a0 += xd[r0*8+f]; a1 += xd[r1*8+f]; a2 += xd[r2*8+f]; a3 += xd[r3*8+f];
        a4 += xd[r4*8+f]; a5 += xd[r5*8+f]; a6 += xd[r6*8+f]; a7 += xd[r7*8+f];
    }
    for (; i + 3 < end; i += 4) {
        int r0 = csr_src[i], r1 = csr_src[i+1], r2 = csr_src[i+2], r3 = csr_src[i+3];
        a0 += xd[r0*8+f]; a1 += xd[r1*8+f]; a2 += xd[r2*8+f]; a3 += xd[r3*8+f];
    }
    for (; i < end; i++) a0 += xd[csr_src[i]*8+f];
    s1[node*8+f] = ((a0+a1)+(a2+a3)) + ((a4+a5)+(a6+a7));
}

// ---------------- pt1: gd1 = dis * relu((dis*s1) @ W1 + b1) ----------------
__global__ void pt1_kernel(const float* __restrict__ s1, const float* __restrict__ dis,
                           const float* __restrict__ W1, const float* __restrict__ b1,
                           float* __restrict__ gd, int n) {
    __shared__ float Ws[5 * F];
    int tid = threadIdx.x;
    if (tid < 5 * F) Ws[tid] = W1[tid];
    __syncthreads();
    int node = blockIdx.x * 8 + (tid >> 5);
    if (node >= n) return;
    int f = tid & 31;
    float dv = dis[node];
    float acc = b1[f];
#pragma unroll
    for (int k = 0; k < 5; k++) acc += dv * s1[node*8+k] * Ws[k*F+f];
    float h = acc > 0.0f ? acc : 0.0f;
    gd[(size_t)node*F+f] = dv * h;
}

// ---------------- 32-wide gather: s[v] = sum gd[r] ----------------
__global__ void gather32_kernel(const float* __restrict__ gd, const int* __restrict__ rowstart,
                                const int* __restrict__ csr_src, float* __restrict__ s, int n) {
    int tid = threadIdx.x;
    int node = blockIdx.x * 8 + (tid >> 5);
    if (node >= n) return;
    int f = tid & 31;
    int start = rowstart[node], end = rowstart[node + 1];
    float a0 = 0, a1 = 0, a2 = 0, a3 = 0, a4 = 0, a5 = 0, a6 = 0, a7 = 0;
    int i = start;
    for (; i + 7 < end; i += 8) {
        int r0 = csr_src[i], r1 = csr_src[i+1], r2 = csr_src[i+2], r3 = csr_src[i+3];
        int r4 = csr_src[i+4], r5 = csr_src[i+5], r6 = csr_src[i+6], r7 = csr_src[i+7];
        a0 += gd[(size_t)r0*F+f]; a1 += gd[(size_t)r1*F+f];
        a2 += gd[(size_t)r2*F+f]; a3 += gd[(size_t)r3*F+f];
        a4 += gd[(size_t)r4*F+f]; a5 += gd[(size_t)r5*F+f];
        a6 += gd[(size_t)r6*F+f]; a7 += gd[(size_t)r7*F+f];
    }
    for (; i + 3 < end; i += 4) {
        int r0 = csr_src[i], r1 = csr_src[i+1], r2 = csr_src[i+2], r3 = csr_src[i+3];
        a0 += gd[(size_t)r0*F+f]; a1 += gd[(size_t)r1*F+f];
        a2 += gd[(size_t)r2*F+f]; a3 += gd[(size_t)r3*F+f];
    }
    for (; i < end; i++) a0 += gd[(size_t)csr_src[i]*F+f];
    s[(size_t)node*F+f] = ((a0+a1)+(a2+a3)) + ((a4+a5)+(a6+a7));
}

// ---------------- pt2: gd = dis * relu((dis*s) @ W + b) ----------------
__global__ void pt2_kernel(const float* __restrict__ s, const float* __restrict__ dis,
                           const float* __restrict__ W, const float* __restrict__ bb,
                           float* __restrict__ gd, int n) {
    __shared__ float Ws[F * F];
    __shared__ float hs[256];
    int tid = threadIdx.x;
    for (int i = tid; i < F * F; i += 256) Ws[i] = W[i];
    int node = blockIdx.x * 8 + (tid >> 5);
    int f = tid & 31;
    float dv = (node < n) ? dis[node] : 0.0f;
    hs[tid] = (node < n) ? dv * s[(size_t)node*F+f] : 0.0f;
    __syncthreads();
    if (node >= n) return;
    const float* hrow = &hs[(tid >> 5) << 5];
    float acc = bb[f];
#pragma unroll
    for (int k = 0; k < F; k++) acc += hrow[k] * Ws[k*F+f];
    float h = acc > 0.0f ? acc : 0.0f;
    gd[(size_t)node*F+f] = dv * h;
}

// ---------------- pt3 + heads fused: h3 = relu((dis*s)@W3+b3); scores; argmax partials ----------------
__global__ void pt3_heads_kernel(const float* __restrict__ s, const float* __restrict__ dis,
                                 const float* __restrict__ W3, const float* __restrict__ b3,
                                 const float* __restrict__ Wd, const float* __restrict__ bd,
                                 const float* __restrict__ Wa, const float* __restrict__ ba,
                                 float* __restrict__ out, float* __restrict__ pmax,
                                 int* __restrict__ pidx, int n) {
    __shared__ float Ws[F * F];
    __shared__ float hs[256];
    __shared__ float gmax[8];
    __shared__ int gidx[8];
    int tid = threadIdx.x;
    for (int i = tid; i < F * F; i += 256) Ws[i] = W3[i];
    int node = blockIdx.x * 8 + (tid >> 5);
    int f = tid & 31;
    float dv = (node < n) ? dis[node] : 0.0f;
    hs[tid] = (node < n) ? dv * s[(size_t)node*F+f] : 0.0f;
    __syncthreads();
    if (node < n) {
        const float* hrow = &hs[(tid >> 5) << 5];
        float acc = b3[f];
#pragma unroll
        for (int k = 0; k < F; k++) acc += hrow[k] * Ws[k*F+f];
        float h = acc > 0.0f ? acc : 0.0f;
        float dterm = h * Wd[f];
        float aterm = h * Wa[f];
#pragma unroll
        for (int off = 16; off > 0; off >>= 1) {
            dterm += __shfl_xor(dterm, off);
            aterm += __shfl_xor(aterm, off);
        }
        if (f == 0) {
            out[node] = dterm + bd[0];
            float asc = aterm + ba[0];
            out[N_NODES + node] = asc;
            gmax[tid >> 5] = asc;
            gidx[tid >> 5] = node;
        }
    } else if (f == 0) {
        gmax[tid >> 5] = -INFINITY;
        gidx[tid >> 5] = 0x7fffffff;
    }
    __syncthreads();
    if (tid == 0) {
        float best = gmax[0]; int bi = gidx[0];
        for (int g = 1; g < 8; g++) {
            if (gmax[g] > best || (gmax[g] == best && gidx[g] < bi)) { best = gmax[g]; bi = gidx[g]; }
        }
        pmax[blockIdx.x] = best;
        pidx[blockIdx.x] = bi;
    }
}

// ---------------- final: global argmax, recompute h3[target], tail heads ----------------
__global__ void final_kernel(const float* __restrict__ pmax, const int* __restrict__ pidx, int nblocks,
                             const float* __restrict__ s, const float* __restrict__ dis,
                             const float* __restrict__ W3, const float* __restrict__ b3,
                             const float* __restrict__ Wt, const float* __restrict__ bt,
                             const float* __restrict__ Wact, const float* __restrict__ bact,
                             float* __restrict__ out) {
    __shared__ float smax[256];
    __shared__ int sidx[256];
    int tid = threadIdx.x;
    float best = -INFINITY; int bi = 0x7fffffff;
    for (int i = tid; i < nblocks; i += 256) {
        float v = pmax[i]; int ix = pidx[i];
        if (v > best || (v == best && ix < bi)) { best = v; bi = ix; }
    }
    smax[tid] = best; sidx[tid] = bi;
    __syncthreads();
    for (int st = 128; st > 0; st >>= 1) {
        if (tid < st) {
            float v2 = smax[tid + st]; int i2 = sidx[tid + st];
            if (v2 > smax[tid] || (v2 == smax[tid] && i2 < sidx[tid])) { smax[tid] = v2; sidx[tid] = i2; }
        }
        __syncthreads();
    }
    __shared__ float ht[F];
    int target = sidx[0];
    if (tid < F) {
        float dv = dis[target];
        float acc = b3[tid];
#pragma unroll
        for (int k = 0; k < F; k++) acc += dv * s[(size_t)target*F+k] * W3[k*F+tid];
        ht[tid] = acc > 0.0f ? acc : 0.0f;
    }
    __syncthreads();
    if (tid < 2) {
        float acc = bt[tid];
#pragma unroll
        for (int k = 0; k < F; k++) acc += ht[k] * Wt[k*2+tid];
        out[2 * N_NODES + tid] = acc;
    } else if (tid < 11) {
        int j = tid - 2;
        float acc = bact[j];
#pragma unroll
        for (int k = 0; k < F; k++) acc += ht[k] * Wact[k*9+j];
        out[2 * N_NODES + 2 + j] = acc;
    }
}

extern "C" void kernel_launch(void* const* d_in, const int* in_sizes, int n_in,
                              void* d_out, int out_size, void* d_ws, size_t ws_size,
                              hipStream_t stream) {
    const float* x  = (const float*)d_in[0];
    const int*   ei = (const int*)d_in[1];
    const int E = in_sizes[1] / 2;
    const int* row = ei;
    const int* col = ei + E;
    const float* W1 = (const float*)d_in[2];
    const float* b1 = (const float*)d_in[3];
    const float* W2 = (const float*)d_in[4];
    const float* b2 = (const float*)d_in[5];
    const float* W3 = (const float*)d_in[6];
    const float* b3 = (const float*)d_in[7];
    const float* Wd = (const float*)d_in[8];
    const float* bd = (const float*)d_in[9];
    const float* Wa = (const float*)d_in[10];
    const float* ba = (const float*)d_in[11];
    const float* Wt = (const float*)d_in[12];
    const float* bt = (const float*)d_in[13];
    const float* Wact = (const float*)d_in[14];
    const float* bact = (const float*)d_in[15];

    float* out = (float*)d_out;
    float* ws  = (float*)d_ws;

    // workspace layout (with aliasing: xd inside gd; storage inside s)
    float*    dis      = ws;                               // N
    float*    gd       = ws + N_NODES;                     // N*F (xd = first N*8)
    float*    s        = gd + (size_t)N_NODES * F;         // N*F  (>= storage: NB*NREP*RCAP = 2.40M < 3.2M)
    unsigned* storage  = (unsigned*)s;
    int*      bcount   = (int*)(s + (size_t)N_NODES * F);  // NB*NREP
    int*      bbase    = bcount + NB * NREP;               // NB
    int*      rowstart = bbase + NB;                       // N+1
    int*      csr_src  = rowstart + N_NODES + 1;           // E
    float*    pmax     = (float*)(csr_src + E);            // 12500
    int*      pidx     = (int*)(pmax + 12500);             // 12500
    float*    xd       = gd;                               // N*8, dead after gather8

    const int B = 256;
    const int nb_nodes8 = (N_NODES + 7) / 8;       // 12500

    // ---- CSR build (bucket-binned, replicated counters) ----
    hipMemsetAsync(bcount, 0, (size_t)NB * NREP * sizeof(int), stream);
    bin_kernel<<<(E + B - 1) / B, B, 0, stream>>>(row, col, bcount, storage, E);
    bscan_kernel<<<1, 1024, 0, stream>>>(bcount, bbase, rowstart);
    csr_build_kernel<<<NB, B, 0, stream>>>(storage, bcount, bbase, rowstart, csr_src, dis, N_NODES);

    // ---- layer 1 (aggregate raw x, 8-wide padded) ----
    xd_kernel<<<(N_NODES * 8 + B - 1) / B, B, 0, stream>>>(x, dis, xd, N_NODES);
    gather8_kernel<<<(N_NODES + 31) / 32, B, 0, stream>>>(xd, rowstart, csr_src, s, N_NODES);
    pt1_kernel<<<nb_nodes8, B, 0, stream>>>(s, dis, W1, b1, gd, N_NODES);

    // ---- layer 2 ----
    gather32_kernel<<<nb_nodes8, B, 0, stream>>>(gd, rowstart, csr_src, s, N_NODES);
    pt2_kernel<<<nb_nodes8, B, 0, stream>>>(s, dis, W2, b2, gd, N_NODES);

    // ---- layer 3 + heads ----
    gather32_kernel<<<nb_nodes8, B, 0, stream>>>(gd, rowstart, csr_src, s, N_NODES);
    pt3_heads_kernel<<<nb_nodes8, B, 0, stream>>>(s, dis, W3, b3, Wd, bd, Wa, ba,
                                                  out, pmax, pidx, N_NODES);
    final_kernel<<<1, B, 0, stream>>>(pmax, pidx, nb_nodes8, s, dis, W3, b3,
                                      Wt, bt, Wact, bact, out);
}

// Round 6
// 339.045 us; speedup vs baseline: 3.8043x; 1.0415x over previous
//
#include <hip/hip_runtime.h>
#include <math.h>

#define N_NODES 100000
#define F 32
#define BUCKET 64
#define NB ((N_NODES + BUCKET - 1) / BUCKET)   // 1563
#define NREP 8
#define RCAP 192        // per-replica cap: mean 128 + ~5.7 sigma

// ---------------- bin edges by (target bucket, replica) ----------------
// replica = (e>>8)&7: constant per 256-edge block -> under round-robin
// blockIdx->XCD mapping, each slot's write frontier is XCD-local, so
// 64B lines fill before eviction (fixes 88MB partial-line WRITE_SIZE).
// Deterministic in e -> correctness never depends on dispatch mapping.
__global__ void bin_kernel(const int* __restrict__ row, const int* __restrict__ col,
                           int* __restrict__ bcount, unsigned* __restrict__ storage, int E) {
    int e = blockIdx.x * 256 + threadIdx.x;
    if (e >= E) return;
    int c = col[e], r = row[e];
    int slot = (c >> 6) * NREP + ((e >> 8) & (NREP - 1));
    int pos = atomicAdd(&bcount[slot], 1);
    if (pos < RCAP)
        storage[(size_t)slot * RCAP + pos] = ((unsigned)(c & 63) << 17) | (unsigned)r;
}

// ---------------- exclusive scan of per-bucket totals (1 block) ----------------
__global__ void bscan_kernel(const int* __restrict__ bcount, int* __restrict__ bbase,
                             int* __restrict__ rowstart) {
    __shared__ int sh[1024];
    int tid = threadIdx.x;
    int b0 = 2 * tid, b1 = 2 * tid + 1;
    int t0 = 0, t1 = 0;
    if (b0 < NB) for (int r = 0; r < NREP; r++) { int c = bcount[b0 * NREP + r]; t0 += (c > RCAP ? RCAP : c); }
    if (b1 < NB) for (int r = 0; r < NREP; r++) { int c = bcount[b1 * NREP + r]; t1 += (c > RCAP ? RCAP : c); }
    int s = t0 + t1;
    sh[tid] = s;
    __syncthreads();
    for (int off = 1; off < 1024; off <<= 1) {
        int v = (tid >= off) ? sh[tid - off] : 0;
        __syncthreads();
        sh[tid] += v;
        __syncthreads();
    }
    int excl = sh[tid] - s;
    if (b0 < NB) bbase[b0] = excl;
    if (b1 < NB) bbase[b1] = excl + t0;
    if (tid == 1023) rowstart[N_NODES] = sh[1023];
}

// ---------------- per-bucket LDS counting sort -> CSR + dis + xd ----------------
__global__ void csr_build_kernel(const unsigned* __restrict__ storage, const int* __restrict__ bcount,
                                 const int* __restrict__ bbase, int* __restrict__ rowstart,
                                 int* __restrict__ csr_src, float* __restrict__ dis,
                                 const float* __restrict__ x, float* __restrict__ xd, int n) {
    __shared__ unsigned sh[NREP * RCAP];
    __shared__ int outloc[NREP * RCAP];
    __shared__ int repbase[NREP + 1];
    __shared__ int hist[BUCKET];
    __shared__ int pre[BUCKET];
    __shared__ int cur[BUCKET];
    __shared__ float dloc[BUCKET];
    int b = blockIdx.x, tid = threadIdx.x;
    if (tid < BUCKET) hist[tid] = 0;
    if (tid == 0) {
        int s = 0;
        for (int r = 0; r < NREP; r++) {
            repbase[r] = s;
            int c = bcount[b * NREP + r];
            s += (c > RCAP ? RCAP : c);
        }
        repbase[NREP] = s;
    }
    __syncthreads();
    int g = tid >> 5, lane = tid & 31;
    {
        int cbeg = repbase[g];
        int clen = repbase[g + 1] - cbeg;
        const unsigned* st = storage + (size_t)(b * NREP + g) * RCAP;
        for (int i = lane; i < clen; i += 32) sh[cbeg + i] = st[i];
    }
    __syncthreads();
    int tot = repbase[NREP];
    for (int i = tid; i < tot; i += 256) atomicAdd(&hist[sh[i] >> 17], 1);
    __syncthreads();
    if (tid < BUCKET) pre[tid] = hist[tid];
    __syncthreads();
    for (int off = 1; off < BUCKET; off <<= 1) {
        int v = 0;
        if (tid < BUCKET && tid >= off) v = pre[tid - off];
        __syncthreads();
        if (tid < BUCKET && tid >= off) pre[tid] += v;
        __syncthreads();
    }
    int base = bbase[b];
    if (tid < BUCKET) {
        int excl = pre[tid] - hist[tid];
        cur[tid] = excl;
        int node = b * BUCKET + tid;
        if (node < n) {
            rowstart[node] = base + excl;
            int d = hist[tid];
            float dv = (d > 0) ? rsqrtf((float)d) : 0.0f;
            dis[node] = dv;
            dloc[tid] = dv;
        }
    }
    __syncthreads();
    // fused xd: xd[node*8+f] = f<5 ? dis*x[node*5+f] : 0  (512 elements, 2 passes)
    for (int i = tid; i < BUCKET * 8; i += 256) {
        int nl = i >> 3, f = i & 7;
        int node = b * BUCKET + nl;
        if (node < n) xd[(size_t)node * 8 + f] = (f < 5) ? dloc[nl] * x[(size_t)node * 5 + f] : 0.0f;
    }
    for (int i = tid; i < tot; i += 256) {
        unsigned p = sh[i];
        int pos = atomicAdd(&cur[p >> 17], 1);
        outloc[pos] = (int)(p & 0x1FFFF);
    }
    __syncthreads();
    for (int i = tid; i < tot; i += 256) csr_src[base + i] = outloc[i];
}

// ---------------- layer-1 gather: s1[v] = sum xd[r]  (8-wide rows) ----------------
__global__ void gather8_kernel(const float* __restrict__ xd, const int* __restrict__ rowstart,
                               const int* __restrict__ csr_src, float* __restrict__ s1, int n) {
    int tid = threadIdx.x;
    int node = blockIdx.x * 32 + (tid >> 3);
    if (node >= n) return;
    int f = tid & 7;
    int start = rowstart[node], end = rowstart[node + 1];
    float a0 = 0, a1 = 0, a2 = 0, a3 = 0, a4 = 0, a5 = 0, a6 = 0, a7 = 0;
    int i = start;
    for (; i + 7 < end; i += 8) {
        int r0 = csr_src[i], r1 = csr_src[i+1], r2 = csr_src[i+2], r3 = csr_src[i+3];
        int r4 = csr_src[i+4], r5 = csr_src[i+5], r6 = csr_src[i+6], r7 = csr_src[i+7];
        a0 += xd[r0*8+f]; a1 += xd[r1*8+f]; a2 += xd[r2*8+f]; a3 += xd[r3*8+f];
        a4 += xd[r4*8+f]; a5 += xd[r5*8+f]; a6 += xd[r6*8+f]; a7 += xd[r7*8+f];
    }
    for (; i + 3 < end; i += 4) {
        int r0 = csr_src[i], r1 = csr_src[i+1], r2 = csr_src[i+2], r3 = csr_src[i+3];
        a0 += xd[r0*8+f]; a1 += xd[r1*8+f]; a2 += xd[r2*8+f]; a3 += xd[r3*8+f];
    }
    for (; i < end; i++) a0 += xd[csr_src[i]*8+f];
    s1[node*8+f] = ((a0+a1)+(a2+a3)) + ((a4+a5)+(a6+a7));
}

// ---------------- pt1: gd1 = dis * relu((dis*s1) @ W1 + b1) ----------------
__global__ void pt1_kernel(const float* __restrict__ s1, const float* __restrict__ dis,
                           const float* __restrict__ W1, const float* __restrict__ b1,
                           float* __restrict__ gd, int n) {
    __shared__ float Ws[5 * F];
    int tid = threadIdx.x;
    if (tid < 5 * F) Ws[tid] = W1[tid];
    __syncthreads();
    int node = blockIdx.x * 8 + (tid >> 5);
    if (node >= n) return;
    int f = tid & 31;
    float dv = dis[node];
    float acc = b1[f];
#pragma unroll
    for (int k = 0; k < 5; k++) acc += dv * s1[node*8+k] * Ws[k*F+f];
    float h = acc > 0.0f ? acc : 0.0f;
    gd[(size_t)node*F+f] = dv * h;
}

// ---------------- 32-wide gather: s[v] = sum gd[r] ----------------
__global__ void gather32_kernel(const float* __restrict__ gd, const int* __restrict__ rowstart,
                                const int* __restrict__ csr_src, float* __restrict__ s, int n) {
    int tid = threadIdx.x;
    int node = blockIdx.x * 8 + (tid >> 5);
    if (node >= n) return;
    int f = tid & 31;
    int start = rowstart[node], end = rowstart[node + 1];
    float a0 = 0, a1 = 0, a2 = 0, a3 = 0, a4 = 0, a5 = 0, a6 = 0, a7 = 0;
    int i = start;
    for (; i + 7 < end; i += 8) {
        int r0 = csr_src[i], r1 = csr_src[i+1], r2 = csr_src[i+2], r3 = csr_src[i+3];
        int r4 = csr_src[i+4], r5 = csr_src[i+5], r6 = csr_src[i+6], r7 = csr_src[i+7];
        a0 += gd[(size_t)r0*F+f]; a1 += gd[(size_t)r1*F+f];
        a2 += gd[(size_t)r2*F+f]; a3 += gd[(size_t)r3*F+f];
        a4 += gd[(size_t)r4*F+f]; a5 += gd[(size_t)r5*F+f];
        a6 += gd[(size_t)r6*F+f]; a7 += gd[(size_t)r7*F+f];
    }
    for (; i + 3 < end; i += 4) {
        int r0 = csr_src[i], r1 = csr_src[i+1], r2 = csr_src[i+2], r3 = csr_src[i+3];
        a0 += gd[(size_t)r0*F+f]; a1 += gd[(size_t)r1*F+f];
        a2 += gd[(size_t)r2*F+f]; a3 += gd[(size_t)r3*F+f];
    }
    for (; i < end; i++) a0 += gd[(size_t)csr_src[i]*F+f];
    s[(size_t)node*F+f] = ((a0+a1)+(a2+a3)) + ((a4+a5)+(a6+a7));
}

// ---------------- pt2: gd = dis * relu((dis*s) @ W + b) ----------------
__global__ void pt2_kernel(const float* __restrict__ s, const float* __restrict__ dis,
                           const float* __restrict__ W, const float* __restrict__ bb,
                           float* __restrict__ gd, int n) {
    __shared__ float Ws[F * F];
    __shared__ float hs[256];
    int tid = threadIdx.x;
    for (int i = tid; i < F * F; i += 256) Ws[i] = W[i];
    int node = blockIdx.x * 8 + (tid >> 5);
    int f = tid & 31;
    float dv = (node < n) ? dis[node] : 0.0f;
    hs[tid] = (node < n) ? dv * s[(size_t)node*F+f] : 0.0f;
    __syncthreads();
    if (node >= n) return;
    const float* hrow = &hs[(tid >> 5) << 5];
    float acc = bb[f];
#pragma unroll
    for (int k = 0; k < F; k++) acc += hrow[k] * Ws[k*F+f];
    float h = acc > 0.0f ? acc : 0.0f;
    gd[(size_t)node*F+f] = dv * h;
}

// ---------------- pt3 + heads fused ----------------
__global__ void pt3_heads_kernel(const float* __restrict__ s, const float* __restrict__ dis,
                                 const float* __restrict__ W3, const float* __restrict__ b3,
                                 const float* __restrict__ Wd, const float* __restrict__ bd,
                                 const float* __restrict__ Wa, const float* __restrict__ ba,
                                 float* __restrict__ out, float* __restrict__ pmax,
                                 int* __restrict__ pidx, int n) {
    __shared__ float Ws[F * F];
    __shared__ float hs[256];
    __shared__ float gmax[8];
    __shared__ int gidx[8];
    int tid = threadIdx.x;
    for (int i = tid; i < F * F; i += 256) Ws[i] = W3[i];
    int node = blockIdx.x * 8 + (tid >> 5);
    int f = tid & 31;
    float dv = (node < n) ? dis[node] : 0.0f;
    hs[tid] = (node < n) ? dv * s[(size_t)node*F+f] : 0.0f;
    __syncthreads();
    if (node < n) {
        const float* hrow = &hs[(tid >> 5) << 5];
        float acc = b3[f];
#pragma unroll
        for (int k = 0; k < F; k++) acc += hrow[k] * Ws[k*F+f];
        float h = acc > 0.0f ? acc : 0.0f;
        float dterm = h * Wd[f];
        float aterm = h * Wa[f];
#pragma unroll
        for (int off = 16; off > 0; off >>= 1) {
            dterm += __shfl_xor(dterm, off);
            aterm += __shfl_xor(aterm, off);
        }
        if (f == 0) {
            out[node] = dterm + bd[0];
            float asc = aterm + ba[0];
            out[N_NODES + node] = asc;
            gmax[tid >> 5] = asc;
            gidx[tid >> 5] = node;
        }
    } else if (f == 0) {
        gmax[tid >> 5] = -INFINITY;
        gidx[tid >> 5] = 0x7fffffff;
    }
    __syncthreads();
    if (tid == 0) {
        float best = gmax[0]; int bi = gidx[0];
        for (int g = 1; g < 8; g++) {
            if (gmax[g] > best || (gmax[g] == best && gidx[g] < bi)) { best = gmax[g]; bi = gidx[g]; }
        }
        pmax[blockIdx.x] = best;
        pidx[blockIdx.x] = bi;
    }
}

// ---------------- final: global argmax, recompute h3[target], tail heads ----------------
__global__ void final_kernel(const float* __restrict__ pmax, const int* __restrict__ pidx, int nblocks,
                             const float* __restrict__ s, const float* __restrict__ dis,
                             const float* __restrict__ W3, const float* __restrict__ b3,
                             const float* __restrict__ Wt, const float* __restrict__ bt,
                             const float* __restrict__ Wact, const float* __restrict__ bact,
                             float* __restrict__ out) {
    __shared__ float smax[256];
    __shared__ int sidx[256];
    int tid = threadIdx.x;
    float best = -INFINITY; int bi = 0x7fffffff;
    for (int i = tid; i < nblocks; i += 256) {
        float v = pmax[i]; int ix = pidx[i];
        if (v > best || (v == best && ix < bi)) { best = v; bi = ix; }
    }
    smax[tid] = best; sidx[tid] = bi;
    __syncthreads();
    for (int st = 128; st > 0; st >>= 1) {
        if (tid < st) {
            float v2 = smax[tid + st]; int i2 = sidx[tid + st];
            if (v2 > smax[tid] || (v2 == smax[tid] && i2 < sidx[tid])) { smax[tid] = v2; sidx[tid] = i2; }
        }
        __syncthreads();
    }
    __shared__ float ht[F];
    int target = sidx[0];
    if (tid < F) {
        float dv = dis[target];
        float acc = b3[tid];
#pragma unroll
        for (int k = 0; k < F; k++) acc += dv * s[(size_t)target*F+k] * W3[k*F+tid];
        ht[tid] = acc > 0.0f ? acc : 0.0f;
    }
    __syncthreads();
    if (tid < 2) {
        float acc = bt[tid];
#pragma unroll
        for (int k = 0; k < F; k++) acc += ht[k] * Wt[k*2+tid];
        out[2 * N_NODES + tid] = acc;
    } else if (tid < 11) {
        int j = tid - 2;
        float acc = bact[j];
#pragma unroll
        for (int k = 0; k < F; k++) acc += ht[k] * Wact[k*9+j];
        out[2 * N_NODES + 2 + j] = acc;
    }
}

extern "C" void kernel_launch(void* const* d_in, const int* in_sizes, int n_in,
                              void* d_out, int out_size, void* d_ws, size_t ws_size,
                              hipStream_t stream) {
    const float* x  = (const float*)d_in[0];
    const int*   ei = (const int*)d_in[1];
    const int E = in_sizes[1] / 2;
    const int* row = ei;
    const int* col = ei + E;
    const float* W1 = (const float*)d_in[2];
    const float* b1 = (const float*)d_in[3];
    const float* W2 = (const float*)d_in[4];
    const float* b2 = (const float*)d_in[5];
    const float* W3 = (const float*)d_in[6];
    const float* b3 = (const float*)d_in[7];
    const float* Wd = (const float*)d_in[8];
    const float* bd = (const float*)d_in[9];
    const float* Wa = (const float*)d_in[10];
    const float* ba = (const float*)d_in[11];
    const float* Wt = (const float*)d_in[12];
    const float* bt = (const float*)d_in[13];
    const float* Wact = (const float*)d_in[14];
    const float* bact = (const float*)d_in[15];

    float* out = (float*)d_out;
    float* ws  = (float*)d_ws;

    // workspace layout (aliasing: xd inside gd; storage inside s)
    float*    dis      = ws;                               // N
    float*    gd       = ws + N_NODES;                     // N*F (xd = first N*8)
    float*    s        = gd + (size_t)N_NODES * F;         // N*F  (>= storage: NB*NREP*RCAP = 2.40M < 3.2M)
    unsigned* storage  = (unsigned*)s;
    int*      bcount   = (int*)(s + (size_t)N_NODES * F);  // NB*NREP
    int*      bbase    = bcount + NB * NREP;               // NB
    int*      rowstart = bbase + NB;                       // N+1
    int*      csr_src  = rowstart + N_NODES + 1;           // E
    float*    pmax     = (float*)(csr_src + E);            // 12500
    int*      pidx     = (int*)(pmax + 12500);             // 12500
    float*    xd       = gd;                               // N*8, dead after gather8

    const int B = 256;
    const int nb_nodes8 = (N_NODES + 7) / 8;       // 12500

    // ---- CSR build (bucket-binned, XCD-local replicated frontiers) ----
    hipMemsetAsync(bcount, 0, (size_t)NB * NREP * sizeof(int), stream);
    bin_kernel<<<(E + B - 1) / B, B, 0, stream>>>(row, col, bcount, storage, E);
    bscan_kernel<<<1, 1024, 0, stream>>>(bcount, bbase, rowstart);
    csr_build_kernel<<<NB, B, 0, stream>>>(storage, bcount, bbase, rowstart, csr_src, dis, x, xd, N_NODES);

    // ---- layer 1 (aggregate raw x, 8-wide padded) ----
    gather8_kernel<<<(N_NODES + 31) / 32, B, 0, stream>>>(xd, rowstart, csr_src, s, N_NODES);
    pt1_kernel<<<nb_nodes8, B, 0, stream>>>(s, dis, W1, b1, gd, N_NODES);

    // ---- layer 2 ----
    gather32_kernel<<<nb_nodes8, B, 0, stream>>>(gd, rowstart, csr_src, s, N_NODES);
    pt2_kernel<<<nb_nodes8, B, 0, stream>>>(s, dis, W2, b2, gd, N_NODES);

    // ---- layer 3 + heads ----
    gather32_kernel<<<nb_nodes8, B, 0, stream>>>(gd, rowstart, csr_src, s, N_NODES);
    pt3_heads_kernel<<<nb_nodes8, B, 0, stream>>>(s, dis, W3, b3, Wd, bd, Wa, ba,
                                                  out, pmax, pidx, N_NODES);
    final_kernel<<<1, B, 0, stream>>>(pmax, pidx, nb_nodes8, s, dis, W3, b3,
                                      Wt, bt, Wact, bact, out);
}